// Round 1
// baseline (305.379 us; speedup 1.0000x reference)
//
#include <hip/hip_runtime.h>

#define C_IN 512
#define D_OUT 128
#define HW 4096
#define NTOK 4096
#define K_CW 16

// ---------------- Phase 1: 1x1 conv as SGEMM: y[b,d,n] = sum_c w[d,c]*x[b,c,n] + bias[d]
__global__ __launch_bounds__(256) void conv_gemm(const float* __restrict__ x,
    const float* __restrict__ w, const float* __restrict__ bias, float* __restrict__ y) {
  const int b = blockIdx.y;
  const int n0 = blockIdx.x * 128;
  const int tid = threadIdx.x;
  const int tx = tid & 15, ty = tid >> 4;
  __shared__ float ws_t[32][136];   // [c][d], padded (136*4B = 16B-aligned rows)
  __shared__ float xs_t[32][136];   // [c][n]
  float acc[8][8];
#pragma unroll
  for (int i = 0; i < 8; ++i)
#pragma unroll
    for (int j = 0; j < 8; ++j) acc[i][j] = 0.f;
  const float* xb = x + (size_t)b * C_IN * HW + n0;
  for (int c0 = 0; c0 < C_IN; c0 += 32) {
    // stage W chunk transposed: w[d][c0+cc] -> ws_t[cc][d]
#pragma unroll
    for (int i = 0; i < 4; ++i) {
      int l = tid + i * 256;          // 1024 float4s = 128 d x 8 cq
      int d = l >> 3, cq = l & 7;
      float4 v = *(const float4*)(w + (size_t)d * C_IN + c0 + cq * 4);
      ws_t[cq * 4 + 0][d] = v.x;
      ws_t[cq * 4 + 1][d] = v.y;
      ws_t[cq * 4 + 2][d] = v.z;
      ws_t[cq * 4 + 3][d] = v.w;
    }
    // stage x chunk: x[b][c0+cc][n0..n0+128) -> xs_t[cc][nn]
#pragma unroll
    for (int i = 0; i < 4; ++i) {
      int l = tid + i * 256;          // 1024 float4s = 32 cc x 32 nq
      int cc = l >> 5, nq = l & 31;
      float4 v = *(const float4*)(xb + (size_t)(c0 + cc) * HW + nq * 4);
      *(float4*)&xs_t[cc][nq * 4] = v;
    }
    __syncthreads();
#pragma unroll
    for (int cc = 0; cc < 32; ++cc) {
      float wf[8], xf[8];
      *(float4*)&wf[0] = *(const float4*)&ws_t[cc][ty * 8];
      *(float4*)&wf[4] = *(const float4*)&ws_t[cc][ty * 8 + 4];
      *(float4*)&xf[0] = *(const float4*)&xs_t[cc][tx * 8];
      *(float4*)&xf[4] = *(const float4*)&xs_t[cc][tx * 8 + 4];
#pragma unroll
      for (int i = 0; i < 8; ++i)
#pragma unroll
        for (int j = 0; j < 8; ++j) acc[i][j] = fmaf(wf[i], xf[j], acc[i][j]);
    }
    __syncthreads();
  }
#pragma unroll
  for (int r = 0; r < 8; ++r) {
    int d = ty * 8 + r;
    float bb = bias[d];
    float* yp = y + ((size_t)b * D_OUT + d) * HW + n0 + tx * 8;
    float4 o0 = {acc[r][0] + bb, acc[r][1] + bb, acc[r][2] + bb, acc[r][3] + bb};
    float4 o1 = {acc[r][4] + bb, acc[r][5] + bb, acc[r][6] + bb, acc[r][7] + bb};
    *(float4*)yp = o0;
    *(float4*)(yp + 4) = o1;
  }
}

// ---------------- Phase 2: BN batch stats per channel d, prefolded to scale/shift
__global__ __launch_bounds__(256) void bn_stats(const float* __restrict__ y,
    const float* __restrict__ bn_g, const float* __restrict__ bn_b,
    float* __restrict__ sc_sh) {
  const int d = blockIdx.x;
  const int tid = threadIdx.x;
  float s = 0.f, s2 = 0.f;
  for (int b = 0; b < 16; ++b) {
    const float4* yp = (const float4*)(y + ((size_t)b * D_OUT + d) * HW);
    for (int i = tid; i < 1024; i += 256) {
      float4 v = yp[i];
      s += v.x + v.y + v.z + v.w;
      s2 += v.x * v.x + v.y * v.y + v.z * v.z + v.w * v.w;
    }
  }
  __shared__ float r1[256], r2[256];
  r1[tid] = s; r2[tid] = s2;
  __syncthreads();
  for (int off = 128; off; off >>= 1) {
    if (tid < off) { r1[tid] += r1[tid + off]; r2[tid] += r2[tid + off]; }
    __syncthreads();
  }
  if (tid == 0) {
    float mu = r1[0] * (1.f / 65536.f);
    float var = r2[0] * (1.f / 65536.f) - mu * mu;
    float sc = rsqrtf(var + 1e-5f) * bn_g[d];
    sc_sh[d] = sc;
    sc_sh[128 + d] = bn_b[d] - mu * sc;
  }
}

// ---------------- Phase 3: per-token scaled-L2 softmax assignment -> A, S0
__global__ __launch_bounds__(256) void assign_softmax(const float* __restrict__ y,
    const float* __restrict__ sc_sh, const float* __restrict__ cw,
    const float* __restrict__ scale, float* __restrict__ A, float* __restrict__ S0) {
  const int b = blockIdx.y;
  const int tid = threadIdx.x;
  const int n = blockIdx.x * 256 + tid;
  __shared__ float cws[16][128];
  __shared__ float c2s[16];
  __shared__ float scs[128], shs[128];
  __shared__ float sscale[16];
  for (int i = tid; i < 2048; i += 256) cws[i >> 7][i & 127] = cw[i];
  if (tid < 128) { scs[tid] = sc_sh[tid]; shs[tid] = sc_sh[128 + tid]; }
  if (tid < 16) sscale[tid] = scale[tid];
  __syncthreads();
  if (tid < 16) {
    float s = 0.f;
#pragma unroll
    for (int d = 0; d < 128; ++d) s += cws[tid][d] * cws[tid][d];
    c2s[tid] = s;
  }
  __syncthreads();
  float dot[16];
#pragma unroll
  for (int k = 0; k < 16; ++k) dot[k] = 0.f;
  float x2 = 0.f;
  const float* yb = y + (size_t)b * D_OUT * HW + n;
#pragma unroll 4
  for (int d = 0; d < 128; ++d) {
    float v = yb[(size_t)d * HW];
    float xv = fmaxf(fmaf(v, scs[d], shs[d]), 0.f);
    x2 = fmaf(xv, xv, x2);
#pragma unroll
    for (int k = 0; k < 16; ++k) dot[k] = fmaf(xv, cws[k][d], dot[k]);
  }
  float sl[16], m = -1e30f;
#pragma unroll
  for (int k = 0; k < 16; ++k) {
    sl[k] = sscale[k] * (x2 + c2s[k] - 2.f * dot[k]);
    m = fmaxf(m, sl[k]);
  }
  float p[16], s = 0.f;
#pragma unroll
  for (int k = 0; k < 16; ++k) { p[k] = __expf(sl[k] - m); s += p[k]; }
  float inv = 1.f / s;
#pragma unroll
  for (int k = 0; k < 16; ++k) p[k] *= inv;
  float4* Ap = (float4*)(A + ((size_t)b * NTOK + n) * 16);
  Ap[0] = make_float4(p[0], p[1], p[2], p[3]);
  Ap[1] = make_float4(p[4], p[5], p[6], p[7]);
  Ap[2] = make_float4(p[8], p[9], p[10], p[11]);
  Ap[3] = make_float4(p[12], p[13], p[14], p[15]);
  const int lane = tid & 63;
#pragma unroll
  for (int k = 0; k < 16; ++k) {
    float v = p[k];
#pragma unroll
    for (int off = 32; off; off >>= 1) v += __shfl_xor(v, off);
    if (lane == 0) atomicAdd(&S0[b * 16 + k], v);
  }
}

// ---------------- Phase 4: E[b,k,d] = sum_n A[b,n,k]*X[b,n,d] - S0[b,k]*cw[k,d]
__global__ __launch_bounds__(256) void aggregate(const float* __restrict__ y,
    const float* __restrict__ sc_sh, const float* __restrict__ A,
    const float* __restrict__ S0, const float* __restrict__ cw,
    float* __restrict__ e_raw) {
  const int b = blockIdx.y;
  const int d0 = blockIdx.x * 4;
  const int tid = threadIdx.x;
  float sc[4], sh[4];
#pragma unroll
  for (int i = 0; i < 4; ++i) { sc[i] = sc_sh[d0 + i]; sh[i] = sc_sh[128 + d0 + i]; }
  float acc[4][16];
#pragma unroll
  for (int i = 0; i < 4; ++i)
#pragma unroll
    for (int k = 0; k < 16; ++k) acc[i][k] = 0.f;
  const float* yb = y + ((size_t)b * D_OUT + d0) * HW;
  const float* Ab = A + (size_t)b * NTOK * 16;
  for (int n = tid; n < NTOK; n += 256) {
    float xv[4];
#pragma unroll
    for (int i = 0; i < 4; ++i) {
      float v = yb[(size_t)i * HW + n];
      xv[i] = fmaxf(fmaf(v, sc[i], sh[i]), 0.f);
    }
    const float4* ap = (const float4*)(Ab + (size_t)n * 16);
    float4 a0 = ap[0], a1 = ap[1], a2 = ap[2], a3 = ap[3];
    float av[16] = {a0.x, a0.y, a0.z, a0.w, a1.x, a1.y, a1.z, a1.w,
                    a2.x, a2.y, a2.z, a2.w, a3.x, a3.y, a3.z, a3.w};
#pragma unroll
    for (int i = 0; i < 4; ++i)
#pragma unroll
      for (int k = 0; k < 16; ++k) acc[i][k] = fmaf(av[k], xv[i], acc[i][k]);
  }
  const int lane = tid & 63, wid = tid >> 6;
  __shared__ float red[4][4][16];
#pragma unroll
  for (int i = 0; i < 4; ++i)
#pragma unroll
    for (int k = 0; k < 16; ++k) {
      float v = acc[i][k];
#pragma unroll
      for (int off = 32; off; off >>= 1) v += __shfl_xor(v, off);
      if (lane == 0) red[wid][i][k] = v;
    }
  __syncthreads();
  if (tid < 64) {
    int i = tid >> 4, k = tid & 15;
    float v = red[0][i][k] + red[1][i][k] + red[2][i][k] + red[3][i][k];
    int d = d0 + i;
    e_raw[(size_t)b * 2048 + k * 128 + d] = v - S0[b * 16 + k] * cw[k * 128 + d];
  }
}

// ---------------- Phase 5: gate[b,c] = sigmoid((lin_w[c]·e)/max(||e||,eps) + lin_b[c])
__global__ __launch_bounds__(256) void gate_kernel(const float* __restrict__ e_raw,
    const float* __restrict__ lin_w, const float* __restrict__ lin_b,
    float* __restrict__ gate) {
  const int b = blockIdx.y;
  const int c0 = blockIdx.x * 64;
  const int tid = threadIdx.x;
  __shared__ float es[2048];
  __shared__ float sred[256];
  __shared__ float s_inv;
  const float* eb = e_raw + (size_t)b * 2048;
  float ss = 0.f;
  for (int i = tid; i < 512; i += 256) {
    float4 v = ((const float4*)eb)[i];
    *(float4*)&es[i * 4] = v;
    ss += v.x * v.x + v.y * v.y + v.z * v.z + v.w * v.w;
  }
  sred[tid] = ss;
  __syncthreads();
  for (int off = 128; off; off >>= 1) {
    if (tid < off) sred[tid] += sred[tid + off];
    __syncthreads();
  }
  if (tid == 0) s_inv = 1.f / fmaxf(sqrtf(sred[0]), 1e-12f);
  __syncthreads();
  const int lane = tid & 63, wid = tid >> 6;
  for (int i = 0; i < 16; ++i) {
    int c = c0 + wid * 16 + i;
    const float* wr = lin_w + (size_t)c * 2048;
    float dotv = 0.f;
#pragma unroll
    for (int j = 0; j < 8; ++j) {
      int idx = j * 64 + lane;     // 512 float4 per row / 64 lanes
      float4 wv = ((const float4*)wr)[idx];
      const float* ep = &es[idx * 4];
      dotv += wv.x * ep[0] + wv.y * ep[1] + wv.z * ep[2] + wv.w * ep[3];
    }
#pragma unroll
    for (int off = 32; off; off >>= 1) dotv += __shfl_xor(dotv, off);
    if (lane == 0) {
      float z = dotv * s_inv + lin_b[c];
      gate[b * 512 + c] = 1.f / (1.f + __expf(-z));
    }
  }
}

// ---------------- Phase 6: out = x * gate[b,c]
__global__ __launch_bounds__(256) void scale_kernel(const float* __restrict__ x,
    const float* __restrict__ gate, float* __restrict__ out, long n4) {
  long i = (long)blockIdx.x * blockDim.x + threadIdx.x;
  long stride = (long)gridDim.x * blockDim.x;
  for (; i < n4; i += stride) {
    float4 v = ((const float4*)x)[i];
    int c = (int)((i >> 10) & 511);   // 1024 float4 per (b,c) plane
    int b = (int)(i >> 19);           // 2^19 float4 per batch
    float g = gate[(b << 9) | c];
    v.x *= g; v.y *= g; v.z *= g; v.w *= g;
    ((float4*)out)[i] = v;
  }
}

extern "C" void kernel_launch(void* const* d_in, const int* in_sizes, int n_in,
                              void* d_out, int out_size, void* d_ws, size_t ws_size,
                              hipStream_t stream) {
  const float* x      = (const float*)d_in[0];
  const float* conv_w = (const float*)d_in[1];
  const float* conv_b = (const float*)d_in[2];
  const float* bn_g   = (const float*)d_in[3];
  const float* bn_b   = (const float*)d_in[4];
  const float* cw     = (const float*)d_in[5];
  const float* scale  = (const float*)d_in[6];
  const float* lin_w  = (const float*)d_in[7];
  const float* lin_b  = (const float*)d_in[8];
  float* out = (float*)d_out;
  float* ws  = (float*)d_ws;

  // ws layout (floats): y[8388608] | A[1048576] | S0[256] | sc_sh[256] | e_raw[32768] | gate[8192]
  float* y     = ws;
  float* A     = ws + 8388608;
  float* S0    = ws + 9437184;
  float* sc_sh = ws + 9437440;
  float* e_raw = ws + 9437696;
  float* gate  = ws + 9470464;

  hipMemsetAsync(S0, 0, 256 * sizeof(float), stream);
  conv_gemm<<<dim3(32, 16), 256, 0, stream>>>(x, conv_w, conv_b, y);
  bn_stats<<<128, 256, 0, stream>>>(y, bn_g, bn_b, sc_sh);
  assign_softmax<<<dim3(16, 16), 256, 0, stream>>>(y, sc_sh, cw, scale, A, S0);
  aggregate<<<dim3(32, 16), 256, 0, stream>>>(y, sc_sh, A, S0, cw, e_raw);
  gate_kernel<<<dim3(8, 16), 256, 0, stream>>>(e_raw, lin_w, lin_b, gate);
  scale_kernel<<<4096, 256, 0, stream>>>(x, gate, out, 8388608L);
}

// Round 2
// 221.988 us; speedup vs baseline: 1.3757x; 1.3757x over previous
//
#include <hip/hip_runtime.h>

typedef __attribute__((ext_vector_type(8))) short short8;
typedef __attribute__((ext_vector_type(4))) float f32x4;

#define LDW 40   // padded LDS row length in ushorts (80 B): b128 frag reads conflict-free

__device__ __forceinline__ unsigned short f2bf(float f) {
  unsigned u = __float_as_uint(f);
  u += 0x7FFFu + ((u >> 16) & 1u);   // RNE
  return (unsigned short)(u >> 16);
}
__device__ __forceinline__ float bf2f(unsigned h) {
  return __uint_as_float(h << 16);
}
__device__ __forceinline__ unsigned long long pack4(float a, float b, float c, float d) {
  return (unsigned long long)f2bf(a) | ((unsigned long long)f2bf(b) << 16)
       | ((unsigned long long)f2bf(c) << 32) | ((unsigned long long)f2bf(d) << 48);
}

// ---------------- Phase 1: conv as bf16 MFMA GEMM, y stored bf16 [b][d][n],
// BN batch-stat partials fused into epilogue.
// Swapped-operand mfma: D[n][d] tile; A = X^T fragment (n x c), B = W^T fragment (c x d).
__global__ __launch_bounds__(256) void conv_mfma(const float* __restrict__ x,
    const float* __restrict__ w, const float* __restrict__ bias,
    unsigned short* __restrict__ y, float* __restrict__ part) {
  const int b = blockIdx.y;
  const int n0 = blockIdx.x * 128;
  const int tid = threadIdx.x;
  const int lane = tid & 63, wv = tid >> 6;
  const int li = lane & 15, q = lane >> 4;
  __shared__ unsigned short Wl[128 * LDW];   // W[d][c-chunk] bf16
  __shared__ unsigned short Xl[128 * LDW];   // X^T[n][c-chunk] bf16
  f32x4 acc[2][8];
#pragma unroll
  for (int m = 0; m < 2; ++m)
#pragma unroll
    for (int r = 0; r < 8; ++r) acc[m][r] = (f32x4){0.f, 0.f, 0.f, 0.f};
  const float* xb = x + (size_t)b * (512 * 4096) + n0;
  const int xn = tid & 127, xch = tid >> 7;
  for (int c0 = 0; c0 < 512; c0 += 32) {
    // stage W[0..128)[c0..c0+32) -> Wl (fp32 -> bf16)
#pragma unroll
    for (int i = 0; i < 4; ++i) {
      int idx = tid + i * 256;
      int d = idx >> 3, c4 = (idx & 7) * 4;
      float4 v = *(const float4*)(w + (size_t)d * 512 + c0 + c4);
      *(unsigned long long*)&Wl[d * LDW + c4] = pack4(v.x, v.y, v.z, v.w);
    }
    // stage X^T[n][c]: 4 strided scalar loads per pack (coalesced across lanes in n)
#pragma unroll
    for (int p = 0; p < 4; ++p) {
      int c = (xch + p * 2) * 4;
      const float* xp = xb + (size_t)(c0 + c) * 4096 + xn;
      float v0 = xp[0];
      float v1 = xp[4096];
      float v2 = xp[2 * 4096];
      float v3 = xp[3 * 4096];
      *(unsigned long long*)&Xl[xn * LDW + c] = pack4(v0, v1, v2, v3);
    }
    __syncthreads();
    short8 af[2], bfr[8];
#pragma unroll
    for (int m = 0; m < 2; ++m)
      af[m] = *(const short8*)&Xl[(32 * wv + 16 * m + li) * LDW + q * 8];
#pragma unroll
    for (int r = 0; r < 8; ++r)
      bfr[r] = *(const short8*)&Wl[(16 * r + li) * LDW + q * 8];
#pragma unroll
    for (int m = 0; m < 2; ++m)
#pragma unroll
      for (int r = 0; r < 8; ++r)
        acc[m][r] = __builtin_amdgcn_mfma_f32_16x16x32_bf16(af[m], bfr[r], acc[m][r], 0, 0, 0);
    __syncthreads();
  }
  // epilogue: +bias, BN partial sums, bf16 store to y[b][d][n]
  float s1[8], s2[8];
#pragma unroll
  for (int r = 0; r < 8; ++r) { s1[r] = 0.f; s2[r] = 0.f; }
#pragma unroll
  for (int r = 0; r < 8; ++r) {
    int d = 16 * r + li;
    float bb = bias[d];
#pragma unroll
    for (int m = 0; m < 2; ++m) {
      int nl = 32 * wv + 16 * m + 4 * q;   // D row = n = 4*(lane>>4)+reg (+16m +32wv)
      float v0 = acc[m][r][0] + bb, v1 = acc[m][r][1] + bb;
      float v2 = acc[m][r][2] + bb, v3 = acc[m][r][3] + bb;
      s1[r] += v0 + v1 + v2 + v3;
      s2[r] += v0 * v0 + v1 * v1 + v2 * v2 + v3 * v3;
      *(unsigned long long*)(y + ((size_t)(b * 128 + d)) * 4096 + n0 + nl) =
          pack4(v0, v1, v2, v3);
    }
  }
#pragma unroll
  for (int r = 0; r < 8; ++r) {
    s1[r] += __shfl_xor(s1[r], 16); s1[r] += __shfl_xor(s1[r], 32);
    s2[r] += __shfl_xor(s2[r], 16); s2[r] += __shfl_xor(s2[r], 32);
  }
  float* red = (float*)Wl;   // 1024 floats, fits in Wl (10 KB)
  if (lane < 16) {
#pragma unroll
    for (int r = 0; r < 8; ++r) {
      red[0 * 512 + wv * 128 + r * 16 + li] = s1[r];
      red[1 * 512 + wv * 128 + r * 16 + li] = s2[r];
    }
  }
  __syncthreads();
  {
    int s = tid >> 7, d = tid & 127;
    float v = red[s * 512 + d] + red[s * 512 + 128 + d]
            + red[s * 512 + 256 + d] + red[s * 512 + 384 + d];
    int blk = b * 32 + blockIdx.x;
    part[(size_t)blk * 256 + s * 128 + d] = v;
  }
}

// ---------------- Phase 2: reduce per-block BN partials -> folded scale/shift
__global__ __launch_bounds__(256) void bn_finalize(const float* __restrict__ part,
    const float* __restrict__ bn_g, const float* __restrict__ bn_b,
    float* __restrict__ sc_sh) {
  const int t = threadIdx.x;
  const int s = t >> 7, d = t & 127;
  float a = 0.f;
  for (int blk = 0; blk < 512; ++blk) a += part[(size_t)blk * 256 + s * 128 + d];
  __shared__ float sums[256];
  sums[t] = a;
  __syncthreads();
  if (t < 128) {
    float mu = sums[t] * (1.f / 65536.f);
    float var = sums[128 + t] * (1.f / 65536.f) - mu * mu;
    float sc = rsqrtf(var + 1e-5f) * bn_g[t];
    sc_sh[t] = sc;
    sc_sh[128 + t] = bn_b[t] - mu * sc;
  }
}

// ---------------- Phase 3: softmax assignment (2 tokens/thread, bf16 y)
__global__ __launch_bounds__(256) void assign_softmax(const unsigned short* __restrict__ y,
    const float* __restrict__ sc_sh, const float* __restrict__ cw,
    const float* __restrict__ scale, float* __restrict__ A, float* __restrict__ S0) {
  const int b = blockIdx.y;
  const int tid = threadIdx.x;
  const int n = (blockIdx.x * 256 + tid) * 2;
  __shared__ float cws[16][128];
  __shared__ float c2s[16], scs[128], shs[128], sscale[16];
  for (int i = tid; i < 2048; i += 256) cws[i >> 7][i & 127] = cw[i];
  if (tid < 128) { scs[tid] = sc_sh[tid]; shs[tid] = sc_sh[128 + tid]; }
  if (tid < 16) sscale[tid] = scale[tid];
  __syncthreads();
  if (tid < 16) {
    float s = 0.f;
#pragma unroll
    for (int d = 0; d < 128; ++d) s += cws[tid][d] * cws[tid][d];
    c2s[tid] = s;
  }
  __syncthreads();
  float dot0[16], dot1[16];
#pragma unroll
  for (int k = 0; k < 16; ++k) { dot0[k] = 0.f; dot1[k] = 0.f; }
  float x20 = 0.f, x21 = 0.f;
  const unsigned short* yb = y + (size_t)b * 524288 + n;
  for (int d4 = 0; d4 < 128; d4 += 4) {
    float xv0[4], xv1[4];
#pragma unroll
    for (int j = 0; j < 4; ++j) {
      unsigned pr = *(const unsigned*)(yb + (size_t)(d4 + j) * 4096);
      float sc = scs[d4 + j], sh = shs[d4 + j];
      float a0 = fmaxf(fmaf(bf2f(pr & 0xFFFFu), sc, sh), 0.f);
      float a1 = fmaxf(fmaf(bf2f(pr >> 16), sc, sh), 0.f);
      xv0[j] = a0; xv1[j] = a1;
      x20 = fmaf(a0, a0, x20); x21 = fmaf(a1, a1, x21);
    }
#pragma unroll
    for (int k = 0; k < 16; ++k) {
      float4 cv = *(const float4*)&cws[k][d4];   // uniform addr -> LDS broadcast
      dot0[k] += xv0[0] * cv.x + xv0[1] * cv.y + xv0[2] * cv.z + xv0[3] * cv.w;
      dot1[k] += xv1[0] * cv.x + xv1[1] * cv.y + xv1[2] * cv.z + xv1[3] * cv.w;
    }
  }
  float p0[16], p1[16];
  {
    float m0 = -1e30f, m1 = -1e30f;
    float sl0[16], sl1[16];
#pragma unroll
    for (int k = 0; k < 16; ++k) {
      sl0[k] = sscale[k] * (x20 + c2s[k] - 2.f * dot0[k]);
      sl1[k] = sscale[k] * (x21 + c2s[k] - 2.f * dot1[k]);
      m0 = fmaxf(m0, sl0[k]); m1 = fmaxf(m1, sl1[k]);
    }
    float s0 = 0.f, s1 = 0.f;
#pragma unroll
    for (int k = 0; k < 16; ++k) {
      p0[k] = __expf(sl0[k] - m0); s0 += p0[k];
      p1[k] = __expf(sl1[k] - m1); s1 += p1[k];
    }
    float i0 = 1.f / s0, i1 = 1.f / s1;
#pragma unroll
    for (int k = 0; k < 16; ++k) { p0[k] *= i0; p1[k] *= i1; }
  }
  float4* Ap = (float4*)(A + ((size_t)b * 4096 + n) * 16);
  Ap[0] = make_float4(p0[0], p0[1], p0[2], p0[3]);
  Ap[1] = make_float4(p0[4], p0[5], p0[6], p0[7]);
  Ap[2] = make_float4(p0[8], p0[9], p0[10], p0[11]);
  Ap[3] = make_float4(p0[12], p0[13], p0[14], p0[15]);
  Ap[4] = make_float4(p1[0], p1[1], p1[2], p1[3]);
  Ap[5] = make_float4(p1[4], p1[5], p1[6], p1[7]);
  Ap[6] = make_float4(p1[8], p1[9], p1[10], p1[11]);
  Ap[7] = make_float4(p1[12], p1[13], p1[14], p1[15]);
  const int lane = tid & 63;
#pragma unroll
  for (int k = 0; k < 16; ++k) {
    float v = p0[k] + p1[k];
#pragma unroll
    for (int off = 32; off; off >>= 1) v += __shfl_xor(v, off);
    if (lane == 0) atomicAdd(&S0[b * 16 + k], v);
  }
}

// ---------------- Phase 4: E[b,k,d] = sum_n A[b,n,k]*X[b,n,d] - S0[b,k]*cw[k,d]
__global__ __launch_bounds__(256) void aggregate(const unsigned short* __restrict__ y,
    const float* __restrict__ sc_sh, const float* __restrict__ A,
    const float* __restrict__ S0, const float* __restrict__ cw,
    float* __restrict__ e_raw) {
  const int b = blockIdx.y;
  const int d0 = blockIdx.x * 4;
  const int tid = threadIdx.x;
  float sc[4], sh[4];
#pragma unroll
  for (int i = 0; i < 4; ++i) { sc[i] = sc_sh[d0 + i]; sh[i] = sc_sh[128 + d0 + i]; }
  float acc[4][16];
#pragma unroll
  for (int i = 0; i < 4; ++i)
#pragma unroll
    for (int k = 0; k < 16; ++k) acc[i][k] = 0.f;
  const unsigned short* yb = y + ((size_t)b * 128 + d0) * 4096;
  const float* Ab = A + (size_t)b * 65536;
  for (int it = 0; it < 8; ++it) {
    int n = (it * 256 + tid) * 2;
    float xv0[4], xv1[4];
#pragma unroll
    for (int i = 0; i < 4; ++i) {
      unsigned pr = *(const unsigned*)(yb + (size_t)i * 4096 + n);
      xv0[i] = fmaxf(fmaf(bf2f(pr & 0xFFFFu), sc[i], sh[i]), 0.f);
      xv1[i] = fmaxf(fmaf(bf2f(pr >> 16), sc[i], sh[i]), 0.f);
    }
    const float4* ap = (const float4*)(Ab + (size_t)n * 16);
    float4 a0 = ap[0], a1 = ap[1], a2 = ap[2], a3 = ap[3];
    float4 b0 = ap[4], b1 = ap[5], b2 = ap[6], b3 = ap[7];
    float av0[16] = {a0.x, a0.y, a0.z, a0.w, a1.x, a1.y, a1.z, a1.w,
                     a2.x, a2.y, a2.z, a2.w, a3.x, a3.y, a3.z, a3.w};
    float av1[16] = {b0.x, b0.y, b0.z, b0.w, b1.x, b1.y, b1.z, b1.w,
                     b2.x, b2.y, b2.z, b2.w, b3.x, b3.y, b3.z, b3.w};
#pragma unroll
    for (int i = 0; i < 4; ++i)
#pragma unroll
      for (int k = 0; k < 16; ++k)
        acc[i][k] += av0[k] * xv0[i] + av1[k] * xv1[i];
  }
  const int lane = tid & 63, wid = tid >> 6;
  __shared__ float red[4][4][16];
#pragma unroll
  for (int i = 0; i < 4; ++i)
#pragma unroll
    for (int k = 0; k < 16; ++k) {
      float v = acc[i][k];
#pragma unroll
      for (int off = 32; off; off >>= 1) v += __shfl_xor(v, off);
      if (lane == 0) red[wid][i][k] = v;
    }
  __syncthreads();
  if (tid < 64) {
    int i = tid >> 4, k = tid & 15;
    float v = red[0][i][k] + red[1][i][k] + red[2][i][k] + red[3][i][k];
    int d = d0 + i;
    e_raw[(size_t)b * 2048 + k * 128 + d] = v - S0[b * 16 + k] * cw[k * 128 + d];
  }
}

// ---------------- Phase 5: gate = sigmoid((lin_w·e)/max(||e||,eps) + lin_b)
__global__ __launch_bounds__(256) void gate_kernel(const float* __restrict__ e_raw,
    const float* __restrict__ lin_w, const float* __restrict__ lin_b,
    float* __restrict__ gate) {
  const int b = blockIdx.y;
  const int c0 = blockIdx.x * 64;
  const int tid = threadIdx.x;
  __shared__ float es[2048];
  __shared__ float sred[256];
  __shared__ float s_inv;
  const float* eb = e_raw + (size_t)b * 2048;
  float ss = 0.f;
  for (int i = tid; i < 512; i += 256) {
    float4 v = ((const float4*)eb)[i];
    *(float4*)&es[i * 4] = v;
    ss += v.x * v.x + v.y * v.y + v.z * v.z + v.w * v.w;
  }
  sred[tid] = ss;
  __syncthreads();
  for (int off = 128; off; off >>= 1) {
    if (tid < off) sred[tid] += sred[tid + off];
    __syncthreads();
  }
  if (tid == 0) s_inv = 1.f / fmaxf(sqrtf(sred[0]), 1e-12f);
  __syncthreads();
  const int lane = tid & 63, wid = tid >> 6;
  for (int i = 0; i < 16; ++i) {
    int c = c0 + wid * 16 + i;
    const float* wr = lin_w + (size_t)c * 2048;
    float dotv = 0.f;
#pragma unroll
    for (int j = 0; j < 8; ++j) {
      int idx = j * 64 + lane;
      float4 wv = ((const float4*)wr)[idx];
      const float* ep = &es[idx * 4];
      dotv += wv.x * ep[0] + wv.y * ep[1] + wv.z * ep[2] + wv.w * ep[3];
    }
#pragma unroll
    for (int off = 32; off; off >>= 1) dotv += __shfl_xor(dotv, off);
    if (lane == 0) {
      float z = dotv * s_inv + lin_b[c];
      gate[b * 512 + c] = 1.f / (1.f + __expf(-z));
    }
  }
}

// ---------------- Phase 6: out = x * gate[b,c]
__global__ __launch_bounds__(256) void scale_kernel(const float* __restrict__ x,
    const float* __restrict__ gate, float* __restrict__ out, long n4) {
  long i = (long)blockIdx.x * blockDim.x + threadIdx.x;
  long stride = (long)gridDim.x * blockDim.x;
  for (; i < n4; i += stride) {
    float4 v = ((const float4*)x)[i];
    int c = (int)((i >> 10) & 511);
    int b = (int)(i >> 19);
    float g = gate[(b << 9) | c];
    v.x *= g; v.y *= g; v.z *= g; v.w *= g;
    ((float4*)out)[i] = v;
  }
}

extern "C" void kernel_launch(void* const* d_in, const int* in_sizes, int n_in,
                              void* d_out, int out_size, void* d_ws, size_t ws_size,
                              hipStream_t stream) {
  const float* x      = (const float*)d_in[0];
  const float* conv_w = (const float*)d_in[1];
  const float* conv_b = (const float*)d_in[2];
  const float* bn_g   = (const float*)d_in[3];
  const float* bn_b   = (const float*)d_in[4];
  const float* cw     = (const float*)d_in[5];
  const float* scale  = (const float*)d_in[6];
  const float* lin_w  = (const float*)d_in[7];
  const float* lin_b  = (const float*)d_in[8];
  float* out = (float*)d_out;
  float* ws  = (float*)d_ws;

  // ws layout (float offsets):
  unsigned short* y = (unsigned short*)ws;      // 8,388,608 ushorts = [0, 4194304) floats
  float* A     = ws + 4194304;                  // 1,048,576
  float* part  = ws + 5242880;                  // 131,072
  float* S0    = ws + 5373952;                  // 256
  float* sc_sh = ws + 5374208;                  // 256
  float* e_raw = ws + 5374464;                  // 32,768
  float* gate  = ws + 5407232;                  // 8,192

  hipMemsetAsync(S0, 0, 256 * sizeof(float), stream);
  conv_mfma<<<dim3(32, 16), 256, 0, stream>>>(x, conv_w, conv_b, y, part);
  bn_finalize<<<1, 256, 0, stream>>>(part, bn_g, bn_b, sc_sh);
  assign_softmax<<<dim3(8, 16), 256, 0, stream>>>(y, sc_sh, cw, scale, A, S0);
  aggregate<<<dim3(32, 16), 256, 0, stream>>>(y, sc_sh, A, S0, cw, e_raw);
  gate_kernel<<<dim3(8, 16), 256, 0, stream>>>(e_raw, lin_w, lin_b, gate);
  scale_kernel<<<4096, 256, 0, stream>>>(x, gate, out, 8388608L);
}